// Round 3
// baseline (367.120 us; speedup 1.0000x reference)
//
#include <hip/hip_runtime.h>
#include <hip/hip_fp16.h>

// Fused guided filter r=8, eps=0.01, (8,3,1024,1024) fp32 — single kernel.
// R3: LDS history ring replaces the lagging-pipeline recompute.
//   Per step k: ONE leading pipeline computes a,b at row p=k+8 (vertical
//   register sums of {x,y,xy,xx} -> LDS row -> 17-tap hbox -> a,b), packs
//   them fp16 into a 17-deep LDS ring; the row q=k-9 needed for the
//   subtract is READ from the ring (written 17 steps earlier) instead of
//   recomputed. Va,Vb (vertical sums of a,b) live in registers; one more
//   LDS round-trip + hbox gives a_mean,b_mean -> out.
//   ds-op count per thread-step: 72 (R2) -> 32: publish V 4w, hbox(a/b
//   inputs) 16r (middle b128 comes from own registers: unit maps u=t+2,
//   w=t, s=t-2), ring 1r+1w, publish Va/Vb 2w, hbox2 8r.
// Raw "s_waitcnt lgkmcnt(0); s_barrier" barriers keep prefetched global
// loads in flight (plain __syncthreads drains vmcnt(0)).
// Tiles: 512 cols x 64 rows, 128 threads (2 waves), LDS 48.8 KB -> 3
// blocks/CU, grid 24*16*2 = 768 = all resident. XCD-swizzled bands.

namespace {
constexpr int RAD = 8;
constexpr int H = 1024, W = 1024;
constexpr int NSL = 24;
constexpr int TW = 512;           // output cols per block
constexpr int ROWS = 64;          // output rows per block
constexpr int NT = 128;           // threads (2 waves)
constexpr int VWID = TW + 32;     // 544 staged V cols  [C0-16, C0+527]
constexpr int ABWID = TW + 16;    // 528 a,b cols       [C0-8,  C0+519]
constexpr int ABUN = ABWID / 4;   // 132 float4 units
constexpr int HD = 17;            // history depth
constexpr float EPS_C = 0.01f;
constexpr int GRID = NSL * (H / ROWS) * (W / TW);  // 768
}

__device__ __forceinline__ float frcp(float v) { return __builtin_amdgcn_rcpf(v); }
__device__ __forceinline__ float4 z4() { return make_float4(0.f, 0.f, 0.f, 0.f); }

__device__ __forceinline__ void bar_lgkm() {
  asm volatile("s_waitcnt lgkmcnt(0)\n\ts_barrier" ::: "memory");
}

__device__ __forceinline__ float inv_span(int p, int n) {
  int lo = p - RAD; lo = lo < 0 ? 0 : lo;
  int hi = p + RAD; hi = hi > n - 1 ? n - 1 : hi;
  return frcp((float)(hi - lo + 1));
}

__device__ __forceinline__ float4 ld4(const float* __restrict__ b, int r, int c) {
  return *reinterpret_cast<const float4*>(b + (size_t)r * W + c);
}

struct VQ { float4 x, y, xy, xx; };
__device__ __forceinline__ void vq_zero(VQ& S) { S.x = z4(); S.y = z4(); S.xy = z4(); S.xx = z4(); }
__device__ __forceinline__ void vq_add(VQ& S, const float4 a, const float4 b) {
  S.x.x += a.x; S.x.y += a.y; S.x.z += a.z; S.x.w += a.w;
  S.y.x += b.x; S.y.y += b.y; S.y.z += b.z; S.y.w += b.w;
  S.xy.x += a.x * b.x; S.xy.y += a.y * b.y; S.xy.z += a.z * b.z; S.xy.w += a.w * b.w;
  S.xx.x += a.x * a.x; S.xx.y += a.y * a.y; S.xx.z += a.z * a.z; S.xx.w += a.w * a.w;
}
__device__ __forceinline__ void vq_sub(VQ& S, const float4 a, const float4 b) {
  S.x.x -= a.x; S.x.y -= a.y; S.x.z -= a.z; S.x.w -= a.w;
  S.y.x -= b.x; S.y.y -= b.y; S.y.z -= b.z; S.y.w -= b.w;
  S.xy.x -= a.x * b.x; S.xy.y -= a.y * b.y; S.xy.z -= a.z * b.z; S.xy.w -= a.w * b.w;
  S.xx.x -= a.x * a.x; S.xx.y -= a.y * a.y; S.xx.z -= a.z * a.z; S.xx.w -= a.w * a.w;
}

__device__ __forceinline__ void hcomb(const float* w, float o[4]) {
  float s = w[0];
#pragma unroll
  for (int i = 1; i <= 16; ++i) s += w[i];
  o[0] = s;
  o[1] = s - w[0] + w[17];
  o[2] = o[1] - w[1] + w[18];
  o[3] = o[2] - w[2] + w[19];
}

// 5-b128-window hbox with the middle b128 supplied from registers (own data)
__device__ __forceinline__ void hbox_own(const float* buf, int base, float4 mid, float o[4]) {
  const float4 va = *reinterpret_cast<const float4*>(buf + base);
  const float4 vb = *reinterpret_cast<const float4*>(buf + base + 4);
  const float4 vd = *reinterpret_cast<const float4*>(buf + base + 12);
  const float4 ve = *reinterpret_cast<const float4*>(buf + base + 16);
  const float w[20] = {va.x, va.y, va.z, va.w, vb.x, vb.y, vb.z, vb.w,
                       mid.x, mid.y, mid.z, mid.w, vd.x, vd.y, vd.z, vd.w,
                       ve.x, ve.y, ve.z, ve.w};
  hcomb(w, o);
}

__device__ __forceinline__ void hbox_full(const float* buf, int base, float o[4]) {
  const float4 va = *reinterpret_cast<const float4*>(buf + base);
  const float4 vb = *reinterpret_cast<const float4*>(buf + base + 4);
  const float4 vc = *reinterpret_cast<const float4*>(buf + base + 8);
  const float4 vd = *reinterpret_cast<const float4*>(buf + base + 12);
  const float4 ve = *reinterpret_cast<const float4*>(buf + base + 16);
  const float w[20] = {va.x, va.y, va.z, va.w, vb.x, vb.y, vb.z, vb.w,
                       vc.x, vc.y, vc.z, vc.w, vd.x, vd.y, vd.z, vd.w,
                       ve.x, ve.y, ve.z, ve.w};
  hcomb(w, o);
}

__device__ __forceinline__ void abmath(const float bx[4], const float by[4],
                                       const float bxy[4], const float bxx[4],
                                       float icy, const float icx[4],
                                       float a[4], float b[4]) {
#pragma unroll
  for (int j = 0; j < 4; ++j) {
    const float n = icy * icx[j];
    const float mx = bx[j] * n, my = by[j] * n;
    const float cov = bxy[j] * n - mx * my;
    const float var = bxx[j] * n - mx * mx;
    const float av = cov * frcp(var + EPS_C);
    a[j] = av; b[j] = my - av * mx;
  }
}

__device__ __forceinline__ uint4 packab(const float a[4], const float b[4]) {
  union { uint4 u; __half2 h[4]; } P;
  P.h[0] = __floats2half2_rn(a[0], a[1]);
  P.h[1] = __floats2half2_rn(a[2], a[3]);
  P.h[2] = __floats2half2_rn(b[0], b[1]);
  P.h[3] = __floats2half2_rn(b[2], b[3]);
  return P.u;
}
__device__ __forceinline__ void unpackab(uint4 u, float a[4], float b[4]) {
  union { uint4 u; __half2 h[4]; } P; P.u = u;
  const float2 f0 = __half22float2(P.h[0]);
  const float2 f1 = __half22float2(P.h[1]);
  const float2 f2 = __half22float2(P.h[2]);
  const float2 f3 = __half22float2(P.h[3]);
  a[0] = f0.x; a[1] = f0.y; a[2] = f1.x; a[3] = f1.y;
  b[0] = f2.x; b[1] = f2.y; b[2] = f3.x; b[3] = f3.y;
}

__device__ __forceinline__ void acc4(float4& d, const float s[4]) {
  d.x += s[0]; d.y += s[1]; d.z += s[2]; d.w += s[3];
}
__device__ __forceinline__ void dec4(float4& d, const float s[4]) {
  d.x -= s[0]; d.y -= s[1]; d.z -= s[2]; d.w -= s[3];
}

__global__ __launch_bounds__(NT, 2) void k_gf(const float* __restrict__ x,
                                              const float* __restrict__ y,
                                              float* __restrict__ out) {
  __shared__ float fS[4][VWID];     // staged vertical sums (4 planes)
  __shared__ float sAB[2][ABWID];   // staged Va, Vb rows
  __shared__ uint4 hist[HD][ABUN];  // fp16-packed a,b ring (17 rows)

  const int t = threadIdx.x;
  int g = blockIdx.x;
  const int xcd = g & 7; g >>= 3;
  const int band = xcd * 2 + (g & 1); g >>= 1;   // [0,16)
  const int ctile = g & 1; g >>= 1;              // [0,2)
  const int slice = g;                           // [0,24)
  const int r0 = band * ROWS;
  const int C0 = ctile * TW;

  const float* xs = x + (size_t)slice * H * W;
  const float* ys = y + (size_t)slice * H * W;
  float* os = out + (size_t)slice * H * W;

  // unit maps: V unit u=t+2 (col C0-8+4t), ab unit w=t (same col),
  // out unit s=t-2 (col C0+4t-8) -> every hbox middle b128 is own regs.
  const int vMc = C0 - 8 + 4 * t;
  const bool vMact = vMc >= 0;                    // (right edge always <W)
  const int uE = (t < 2) ? t : (128 + t);         // extras: {0,1,130..135}
  const int vEc = C0 - 16 + 4 * uE;
  const bool vEact = (t < 8) && (vEc >= 0) && (vEc < W);
  const bool abMact = vMact;
  const int wE = 128 + (t - 64);                  // extras on wave 1
  const int aEc = C0 - 8 + 4 * wE;
  const bool abEact = (t >= 64) && (t < 68) && (aEc < W);
  const int sIdx = (t >= 2) ? (t - 2) : (126 + t);
  const int oc = C0 + 4 * sIdx;
  const bool outMain = (t >= 2);

  float icxA[4], icxO[4], icxE[4];
#pragma unroll
  for (int j = 0; j < 4; ++j) {
    icxA[j] = inv_span(vMc + j, W);
    icxO[j] = inv_span(oc + j, W);
    icxE[j] = inv_span(aEc + j, W);
  }

  // zero staging (inactive units stay zero = the pad); ring needs no init
  for (int i = t; i < 4 * VWID; i += NT) (&fS[0][0])[i] = 0.f;
  for (int i = t; i < 2 * ABWID; i += NT) (&sAB[0][0])[i] = 0.f;
  __syncthreads();

  VQ M, E; vq_zero(M); vq_zero(E);
  float4 VaM = z4(), VbM = z4(), VaE = z4(), VbE = z4();

  // build V window centered at cstart
  const int cstart = (r0 - 9 < 0) ? 0 : (r0 - 9);
  {
    int lo = cstart - RAD; if (lo < 0) lo = 0;
    for (int rr = lo; rr <= cstart + RAD; ++rr) {
      if (vMact) vq_add(M, ld4(xs, rr, vMc), ld4(ys, rr, vMc));
      if (vEact) vq_add(E, ld4(xs, rr, vEc), ld4(ys, rr, vEc));
    }
  }

  // ---- init: centers cstart..r0+7 — fill ring, accumulate Va,Vb ----
  for (int c = cstart; c <= r0 + 7; ++c) {
    const int ra = c + 9, rs = c - RAD;           // ra < H always here
    float4 xa = z4(), ya = z4(), xr = z4(), yr = z4();
    float4 xae = z4(), yae = z4(), xre = z4(), yre = z4();
    if (vMact) {
      xa = ld4(xs, ra, vMc); ya = ld4(ys, ra, vMc);
      if (rs >= 0) { xr = ld4(xs, rs, vMc); yr = ld4(ys, rs, vMc); }
    }
    if (vEact) {
      xae = ld4(xs, ra, vEc); yae = ld4(ys, ra, vEc);
      if (rs >= 0) { xre = ld4(xs, rs, vEc); yre = ld4(ys, rs, vEc); }
    }
    if (vMact) {
      *reinterpret_cast<float4*>(&fS[0][4 * (t + 2)]) = M.x;
      *reinterpret_cast<float4*>(&fS[1][4 * (t + 2)]) = M.y;
      *reinterpret_cast<float4*>(&fS[2][4 * (t + 2)]) = M.xy;
      *reinterpret_cast<float4*>(&fS[3][4 * (t + 2)]) = M.xx;
    }
    if (vEact) {
      *reinterpret_cast<float4*>(&fS[0][4 * uE]) = E.x;
      *reinterpret_cast<float4*>(&fS[1][4 * uE]) = E.y;
      *reinterpret_cast<float4*>(&fS[2][4 * uE]) = E.xy;
      *reinterpret_cast<float4*>(&fS[3][4 * uE]) = E.xx;
    }
    bar_lgkm();  // A
    const float icy = inv_span(c, H);
    if (abMact) {
      float bx[4], by[4], bxy[4], bxx[4], a4[4], b4[4];
      hbox_own(&fS[0][0], 4 * t, M.x, bx);
      hbox_own(&fS[1][0], 4 * t, M.y, by);
      hbox_own(&fS[2][0], 4 * t, M.xy, bxy);
      hbox_own(&fS[3][0], 4 * t, M.xx, bxx);
      abmath(bx, by, bxy, bxx, icy, icxA, a4, b4);
      hist[c % HD][t] = packab(a4, b4);
      acc4(VaM, a4); acc4(VbM, b4);
    }
    if (abEact) {
      float bx[4], by[4], bxy[4], bxx[4], a4[4], b4[4];
      hbox_full(&fS[0][0], 4 * wE, bx);
      hbox_full(&fS[1][0], 4 * wE, by);
      hbox_full(&fS[2][0], 4 * wE, bxy);
      hbox_full(&fS[3][0], 4 * wE, bxx);
      abmath(bx, by, bxy, bxx, icy, icxE, a4, b4);
      hist[c % HD][wE] = packab(a4, b4);
      acc4(VaE, a4); acc4(VbE, b4);
    }
    if (vMact) { vq_add(M, xa, ya); vq_sub(M, xr, yr); }
    if (vEact) { vq_add(E, xae, yae); vq_sub(E, xre, yre); }
    bar_lgkm();  // C
  }

  // ---- steady: one output row per step ----
  for (int k = r0; k < r0 + ROWS; ++k) {
    const int ra = k + 17;
    const bool doA = ra < H;
    float4 xa = z4(), ya = z4(), xk = z4(), yk = z4();
    float4 xae = z4(), yae = z4(), xke = z4(), yke = z4(), xo2 = z4();
    if (vMact) {
      if (doA) { xa = ld4(xs, ra, vMc); ya = ld4(ys, ra, vMc); }
      xk = ld4(xs, k, vMc); yk = ld4(ys, k, vMc);   // V-sub; also out-x (s=t-2)
    }
    if (vEact) {
      if (doA) { xae = ld4(xs, ra, vEc); yae = ld4(ys, ra, vEc); }
      xke = ld4(xs, k, vEc); yke = ld4(ys, k, vEc);
    }
    if (t < 2) xo2 = ld4(xs, k, oc);                // extra out units' x
    if (vMact) {
      *reinterpret_cast<float4*>(&fS[0][4 * (t + 2)]) = M.x;
      *reinterpret_cast<float4*>(&fS[1][4 * (t + 2)]) = M.y;
      *reinterpret_cast<float4*>(&fS[2][4 * (t + 2)]) = M.xy;
      *reinterpret_cast<float4*>(&fS[3][4 * (t + 2)]) = M.xx;
    }
    if (vEact) {
      *reinterpret_cast<float4*>(&fS[0][4 * uE]) = E.x;
      *reinterpret_cast<float4*>(&fS[1][4 * uE]) = E.y;
      *reinterpret_cast<float4*>(&fS[2][4 * uE]) = E.xy;
      *reinterpret_cast<float4*>(&fS[3][4 * uE]) = E.xx;
    }
    bar_lgkm();  // A

    const int p = k + 8, q = k - 9;
    const float icyp = inv_span(p, H);
    if (abMact) {
      float a4[4] = {0, 0, 0, 0}, b4[4] = {0, 0, 0, 0};
      if (p < H) {
        float bx[4], by[4], bxy[4], bxx[4];
        hbox_own(&fS[0][0], 4 * t, M.x, bx);
        hbox_own(&fS[1][0], 4 * t, M.y, by);
        hbox_own(&fS[2][0], 4 * t, M.xy, bxy);
        hbox_own(&fS[3][0], 4 * t, M.xx, bxx);
        abmath(bx, by, bxy, bxx, icyp, icxA, a4, b4);
      }
      if (q >= 0) {
        float aq[4], bq[4];
        unpackab(hist[q % HD][t], aq, bq);   // read old before write (same slot)
        dec4(VaM, aq); dec4(VbM, bq);
      }
      if (p < H) {
        hist[p % HD][t] = packab(a4, b4);
        acc4(VaM, a4); acc4(VbM, b4);
      }
      *reinterpret_cast<float4*>(&sAB[0][4 * t]) = VaM;
      *reinterpret_cast<float4*>(&sAB[1][4 * t]) = VbM;
    }
    if (abEact) {
      float a4[4] = {0, 0, 0, 0}, b4[4] = {0, 0, 0, 0};
      if (p < H) {
        float bx[4], by[4], bxy[4], bxx[4];
        hbox_full(&fS[0][0], 4 * wE, bx);
        hbox_full(&fS[1][0], 4 * wE, by);
        hbox_full(&fS[2][0], 4 * wE, bxy);
        hbox_full(&fS[3][0], 4 * wE, bxx);
        abmath(bx, by, bxy, bxx, icyp, icxE, a4, b4);
      }
      if (q >= 0) {
        float aq[4], bq[4];
        unpackab(hist[q % HD][wE], aq, bq);
        dec4(VaE, aq); dec4(VbE, bq);
      }
      if (p < H) {
        hist[p % HD][wE] = packab(a4, b4);
        acc4(VaE, a4); acc4(VbE, b4);
      }
      *reinterpret_cast<float4*>(&sAB[0][4 * wE]) = VaE;
      *reinterpret_cast<float4*>(&sAB[1][4 * wE]) = VbE;
    }
    bar_lgkm();  // B

    float Sa[4], Sb[4];
    if (outMain) {
      hbox_own(&sAB[0][0], 4 * sIdx, VaM, Sa);
      hbox_own(&sAB[1][0], 4 * sIdx, VbM, Sb);
    } else {
      hbox_full(&sAB[0][0], 4 * sIdx, Sa);
      hbox_full(&sAB[1][0], 4 * sIdx, Sb);
    }
    const float icy = inv_span(k, H);
    const float4 xv = outMain ? xk : xo2;
    float4 o;
    {
      const float n0 = icy * icxO[0], n1 = icy * icxO[1];
      const float n2 = icy * icxO[2], n3 = icy * icxO[3];
      o.x = Sa[0] * n0 * xv.x + Sb[0] * n0;
      o.y = Sa[1] * n1 * xv.y + Sb[1] * n1;
      o.z = Sa[2] * n2 * xv.z + Sb[2] * n2;
      o.w = Sa[3] * n3 * xv.w + Sb[3] * n3;
    }
    *reinterpret_cast<float4*>(os + (size_t)k * W + oc) = o;

    if (vMact) { vq_add(M, xa, ya); vq_sub(M, xk, yk); }
    if (vEact) { vq_add(E, xae, yae); vq_sub(E, xke, yke); }
    bar_lgkm();  // C
  }
}

extern "C" void kernel_launch(void* const* d_in, const int* in_sizes, int n_in,
                              void* d_out, int out_size, void* d_ws, size_t ws_size,
                              hipStream_t stream) {
  const float* x = (const float*)d_in[0];
  const float* y = (const float*)d_in[1];
  float* out = (float*)d_out;
  k_gf<<<GRID, NT, 0, stream>>>(x, y, out);
}